// Round 6
// baseline (390.084 us; speedup 1.0000x reference)
//
#include <hip/hip_runtime.h>
#include <hip/hip_bf16.h>

#define N_NODES 8192
#define F_INDIM 512
#define H1DIM   256
#define H2DIM   64
#define RCAP    128   // bucket capacity per row (max degree ~60, 12-sigma margin)

typedef __bf16 bf16x8 __attribute__((ext_vector_type(8)));
typedef __bf16 bf16x4 __attribute__((ext_vector_type(4)));
typedef __bf16 bf16x2 __attribute__((ext_vector_type(2)));
typedef float  floatx4 __attribute__((ext_vector_type(4)));
typedef float  floatx2 __attribute__((ext_vector_type(2)));

// ---------------- fused: scatter_bucket (blocks < nc) || transpose_cast_w ---
__global__ __launch_bounds__(256) void fused_scatter_transw(
        const int* __restrict__ rows, const int* __restrict__ cols,
        const float* __restrict__ vals, int* __restrict__ deg,
        int* __restrict__ csr_col, float* __restrict__ csr_val, int e, int nc,
        const float* __restrict__ W1, const float* __restrict__ W2,
        const float* __restrict__ W3,
        __bf16* __restrict__ w1th, __bf16* __restrict__ w1tl,
        __bf16* __restrict__ w23th, __bf16* __restrict__ w23tl) {
    __shared__ float tile[32][33];
    const int b = blockIdx.x;
    if (b < nc) {
        int i = b * 256 + threadIdx.x;
        if (i < e) {
            int r = rows[i];
            int slot = atomicAdd(&deg[r], 1);
            csr_col[(size_t)r * RCAP + slot] = cols[i];
            csr_val[(size_t)r * RCAP + slot] = vals[i];
        }
        return;
    }
    const int bb = b - nc;
    const float* src; __bf16 *oh, *ol; int N, rowoff, outld, kt, nt;
    if (bb < 128)      { src = W1; N = 256; oh = w1th;  ol = w1tl;  rowoff = 0;
                         outld = 512; kt = bb >> 3; nt = bb & 7; }
    else if (bb < 144) { src = W2; N = 64;  oh = w23th; ol = w23tl; rowoff = 0;
                         outld = 256; kt = (bb - 128) >> 1; nt = (bb - 128) & 1; }
    else               { src = W3; N = 64;  oh = w23th; ol = w23tl; rowoff = 64;
                         outld = 256; kt = (bb - 144) >> 1; nt = (bb - 144) & 1; }
    const int tx = threadIdx.x & 31, ty = threadIdx.x >> 5;   // 32 x 8
#pragma unroll
    for (int j = 0; j < 4; ++j)
        tile[ty + 8 * j][tx] = src[(size_t)(kt * 32 + ty + 8 * j) * N + nt * 32 + tx];
    __syncthreads();
#pragma unroll
    for (int j = 0; j < 4; ++j) {
        int n = nt * 32 + ty + 8 * j;
        int k = kt * 32 + tx;
        float v = tile[tx][ty + 8 * j];
        __bf16 h = (__bf16)v;
        oh[(size_t)(rowoff + n) * outld + k] = h;
        ol[(size_t)(rowoff + n) * outld + k] = (__bf16)(v - (float)h);
    }
}

// ---------------- gemm1: support = x @ W1 via split-bf16 MFMA ----------------
// BM=64, BN=128, BK=32, 4 waves (2x2), wave tile 32x64.
// A staged in LDS (f32->split during stage); B fragments read DIRECT from
// global (weights are 512 KB, L2-hot across all 256 blocks) -- no B LDS,
// no B staging stalls.
__global__ __launch_bounds__(256) void gemm1_mfma(const float* __restrict__ x,
                                                  const __bf16* __restrict__ bth,
                                                  const __bf16* __restrict__ btl,
                                                  float* __restrict__ C) {
    constexpr int K = F_INDIM, NN = H1DIM, LDSW = 40;
    __shared__ __bf16 Ah[64 * LDSW], Al[64 * LDSW];
    const int tid = threadIdx.x;
    const int g = blockIdx.x;
    const int m0 = (g >> 1) * 64, n0 = (g & 1) * 128;
    const int lane = tid & 63, wv = tid >> 6;
    const int wm = wv >> 1, wn = wv & 1;
    const int r16 = lane & 15, q = lane >> 4;
    const int sr = tid >> 2, sc = (tid & 3) * 8;   // A stage: 64 rows x 4 chunks of 8
    floatx4 acc[2][4] = {};

    for (int k0 = 0; k0 < K; k0 += 32) {
        floatx4 xa0 = *(const floatx4*)&x[(size_t)(m0 + sr) * K + k0 + sc];
        floatx4 xa1 = *(const floatx4*)&x[(size_t)(m0 + sr) * K + k0 + sc + 4];
        bf16x8 va, va2;
#pragma unroll
        for (int j = 0; j < 4; ++j) {
            __bf16 h0 = (__bf16)xa0[j];
            va[j] = h0; va2[j] = (__bf16)(xa0[j] - (float)h0);
            __bf16 h1 = (__bf16)xa1[j];
            va[4 + j] = h1; va2[4 + j] = (__bf16)(xa1[j] - (float)h1);
        }
        __syncthreads();
        *(bf16x8*)&Ah[sr * LDSW + sc] = va;
        *(bf16x8*)&Al[sr * LDSW + sc] = va2;
        __syncthreads();
        bf16x8 ah[2], al[2], bh[4], bl[4];
#pragma unroll
        for (int mt = 0; mt < 2; ++mt) {
            ah[mt] = *(const bf16x8*)&Ah[(wm * 32 + mt * 16 + r16) * LDSW + q * 8];
            al[mt] = *(const bf16x8*)&Al[(wm * 32 + mt * 16 + r16) * LDSW + q * 8];
        }
#pragma unroll
        for (int nt = 0; nt < 4; ++nt) {
            size_t boff = (size_t)(n0 + wn * 64 + nt * 16 + r16) * K + k0 + q * 8;
            bh[nt] = *(const bf16x8*)&bth[boff];
            bl[nt] = *(const bf16x8*)&btl[boff];
        }
#pragma unroll
        for (int mt = 0; mt < 2; ++mt)
#pragma unroll
            for (int nt = 0; nt < 4; ++nt) {
                acc[mt][nt] = __builtin_amdgcn_mfma_f32_16x16x32_bf16(ah[mt], bh[nt], acc[mt][nt], 0, 0, 0);
                acc[mt][nt] = __builtin_amdgcn_mfma_f32_16x16x32_bf16(ah[mt], bl[nt], acc[mt][nt], 0, 0, 0);
                acc[mt][nt] = __builtin_amdgcn_mfma_f32_16x16x32_bf16(al[mt], bh[nt], acc[mt][nt], 0, 0, 0);
            }
    }
#pragma unroll
    for (int mt = 0; mt < 2; ++mt)
#pragma unroll
        for (int nt = 0; nt < 4; ++nt)
#pragma unroll
            for (int i = 0; i < 4; ++i) {
                int row = m0 + wm * 32 + mt * 16 + q * 4 + i;
                int col = n0 + wn * 64 + nt * 16 + r16;
                C[(size_t)row * NN + col] = acc[mt][nt][i];
            }
}

// ---------------- fused spmm_h1 + gemm23 (bucket CSR, unroll-8 gather) ------
// Phase 2 B fragments read direct from global (128 KB weights, L2-hot):
// no B LDS, ONE barrier total in phase 2. LDS 41->21 KB => 4 blocks/CU
// (was 3) for better gather latency hiding.
__global__ __launch_bounds__(512) void spmm_gemm23(const int* __restrict__ rowdeg,
                                                   const int* __restrict__ csr_col,
                                                   const float* __restrict__ csr_val,
                                                   const float* __restrict__ support,
                                                   const __bf16* __restrict__ bth,
                                                   const __bf16* __restrict__ btl,
                                                   float* __restrict__ t23) {
    constexpr int LDA = 264;
    __shared__ __bf16 Ah[16 * LDA], Al[16 * LDA];
    __shared__ int   s_col[8][64];
    __shared__ float s_val[8][64];
    const int tid = threadIdx.x;
    const int w = tid >> 6, lane = tid & 63;
    const int m0 = blockIdx.x * 16;

    const float2* in2 = (const float2*)support;
#pragma unroll
    for (int p = 0; p < 2; ++p) {
        const int coff = p * 64;
#pragma unroll
        for (int ri = 0; ri < 2; ++ri) {
            const int rl = w * 2 + ri;
            const int r = m0 + rl;
            const int beg = r * RCAP;
            const int deg = rowdeg[r];
            float ax = 0.f, ay = 0.f;
            for (int base = 0; base < deg; base += 64) {
                int m = deg - base; if (m > 64) m = 64;
                if (lane < m) {
                    s_col[w][lane] = csr_col[beg + base + lane];
                    s_val[w][lane] = csr_val[beg + base + lane];
                }
                int e = 0;
                for (; e + 8 <= m; e += 8) {
                    float2 xv[8]; float vv[8];
#pragma unroll
                    for (int j = 0; j < 8; ++j) {
                        xv[j] = in2[(size_t)s_col[w][e + j] * 128 + coff + lane];
                        vv[j] = s_val[w][e + j];
                    }
#pragma unroll
                    for (int j = 0; j < 8; ++j) { ax += vv[j] * xv[j].x; ay += vv[j] * xv[j].y; }
                }
                for (; e + 4 <= m; e += 4) {
                    float2 xv[4]; float vv[4];
#pragma unroll
                    for (int j = 0; j < 4; ++j) {
                        xv[j] = in2[(size_t)s_col[w][e + j] * 128 + coff + lane];
                        vv[j] = s_val[w][e + j];
                    }
#pragma unroll
                    for (int j = 0; j < 4; ++j) { ax += vv[j] * xv[j].x; ay += vv[j] * xv[j].y; }
                }
                for (; e < m; ++e) {
                    float2 xv = in2[(size_t)s_col[w][e] * 128 + coff + lane];
                    float v = s_val[w][e];
                    ax += v * xv.x;
                    ay += v * xv.y;
                }
            }
            float rx = fmaxf(ax, 0.f), ry = fmaxf(ay, 0.f);
            __bf16 hx = (__bf16)rx, hy = (__bf16)ry;
            bf16x2 hv = {hx, hy};
            bf16x2 lv = {(__bf16)(rx - (float)hx), (__bf16)(ry - (float)hy)};
            const int kb = p * 128 + lane * 2;
            *(bf16x2*)&Ah[rl * LDA + kb] = hv;
            *(bf16x2*)&Al[rl * LDA + kb] = lv;
        }
    }
    __syncthreads();   // A tiles complete; phase 2 is barrier-free from here
    const int r16 = lane & 15, q = lane >> 4;
    floatx4 acc = {};                      // wave w owns out-cols w*16..w*16+15
#pragma unroll
    for (int k0 = 0; k0 < H1DIM; k0 += 32) {
        bf16x8 ah = *(const bf16x8*)&Ah[r16 * LDA + k0 + q * 8];
        bf16x8 al = *(const bf16x8*)&Al[r16 * LDA + k0 + q * 8];
        size_t boff = (size_t)(w * 16 + r16) * H1DIM + k0 + q * 8;
        bf16x8 bh = *(const bf16x8*)&bth[boff];
        bf16x8 bl = *(const bf16x8*)&btl[boff];
        acc = __builtin_amdgcn_mfma_f32_16x16x32_bf16(ah, bh, acc, 0, 0, 0);
        acc = __builtin_amdgcn_mfma_f32_16x16x32_bf16(ah, bl, acc, 0, 0, 0);
        acc = __builtin_amdgcn_mfma_f32_16x16x32_bf16(al, bh, acc, 0, 0, 0);
    }
#pragma unroll
    for (int i = 0; i < 4; ++i) {
        int row = m0 + q * 4 + i;
        int col = w * 16 + r16;
        t23[(size_t)row * 128 + col] = acc[i];
    }
}

// ---------------- spmm23: mu/z/logvar/zb (bucket CSR, unroll-8) -------------
__global__ __launch_bounds__(256) void spmm_mu_logvar(const int* __restrict__ rowdeg,
                                                      const int* __restrict__ csr_col,
                                                      const float* __restrict__ csr_val,
                                                      const float* __restrict__ t23,
                                                      float* __restrict__ mu,
                                                      float* __restrict__ z,
                                                      float* __restrict__ logvar,
                                                      __bf16* __restrict__ zb) {
    __shared__ int   s_col[4][64];
    __shared__ float s_val[4][64];
    const int tid = threadIdx.x;
    const int w = tid >> 6, lane = tid & 63;
    const int r = blockIdx.x * 4 + w;
    const int beg = r * RCAP;
    const int deg = rowdeg[r];
    const float2* in2 = (const float2*)t23;
    float ax = 0.f, ay = 0.f;
    for (int base = 0; base < deg; base += 64) {
        int m = deg - base; if (m > 64) m = 64;
        if (lane < m) {
            s_col[w][lane] = csr_col[beg + base + lane];
            s_val[w][lane] = csr_val[beg + base + lane];
        }
        int e = 0;
        for (; e + 8 <= m; e += 8) {
            float2 xv[8]; float vv[8];
#pragma unroll
            for (int j = 0; j < 8; ++j) {
                xv[j] = in2[(size_t)s_col[w][e + j] * 64 + lane];
                vv[j] = s_val[w][e + j];
            }
#pragma unroll
            for (int j = 0; j < 8; ++j) { ax += vv[j] * xv[j].x; ay += vv[j] * xv[j].y; }
        }
        for (; e + 4 <= m; e += 4) {
            float2 xv[4]; float vv[4];
#pragma unroll
            for (int j = 0; j < 4; ++j) {
                xv[j] = in2[(size_t)s_col[w][e + j] * 64 + lane];
                vv[j] = s_val[w][e + j];
            }
#pragma unroll
            for (int j = 0; j < 4; ++j) { ax += vv[j] * xv[j].x; ay += vv[j] * xv[j].y; }
        }
        for (; e < m; ++e) {
            float2 xv = in2[(size_t)s_col[w][e] * 64 + lane];
            float v = s_val[w][e];
            ax += v * xv.x;
            ay += v * xv.y;
        }
    }
    if (lane < 32) {
        size_t o2 = (size_t)r * 32 + lane;
        float2 v = {ax, ay};
        ((float2*)mu)[o2] = v;
        ((float2*)z)[o2] = v;
        bf16x2 b = {(__bf16)ax, (__bf16)ay};
        *(bf16x2*)&zb[(size_t)r * H2DIM + lane * 2] = b;
    } else {
        size_t o2 = (size_t)r * 32 + (lane - 32);
        float2 v = {ax, ay};
        ((float2*)logvar)[o2] = v;
    }
}

// ---------------- adj_recon = z @ z^T: MFMA + LDS-staged plain f4 stores ----
__global__ __launch_bounds__(256) void zzt_mfma(const __bf16* __restrict__ z,
                                                float* __restrict__ C) {
    constexpr int LDT = 132;
    __shared__ float tile[128 * LDT];
    const int tid = threadIdx.x;
    const int lane = tid & 63;
    const int wave = tid >> 6;
    const int wm = wave >> 1, wn = wave & 1;
    const int bm = blockIdx.y * 128, bn = blockIdx.x * 128;
    const int m0 = bm + wm * 64;
    const int n0 = bn + wn * 64;
    const int r16 = lane & 15;
    const int quad = lane >> 4;

    floatx4 acc[4][4] = {};
    const char* zc = (const char*)z;

#pragma unroll
    for (int h = 0; h < 2; ++h) {
        bf16x8 a[4], b[4];
#pragma unroll
        for (int mt = 0; mt < 4; ++mt)
            a[mt] = *(const bf16x8*)(zc + (m0 + mt * 16 + r16) * 128 + h * 64 + quad * 16);
#pragma unroll
        for (int nt = 0; nt < 4; ++nt)
            b[nt] = *(const bf16x8*)(zc + (n0 + nt * 16 + r16) * 128 + h * 64 + quad * 16);
#pragma unroll
        for (int mt = 0; mt < 4; ++mt)
#pragma unroll
            for (int nt = 0; nt < 4; ++nt)
                acc[mt][nt] = __builtin_amdgcn_mfma_f32_16x16x32_bf16(a[mt], b[nt], acc[mt][nt], 0, 0, 0);
    }

#pragma unroll
    for (int mt = 0; mt < 4; ++mt)
#pragma unroll
        for (int nt = 0; nt < 4; ++nt)
#pragma unroll
            for (int rr = 0; rr < 4; ++rr)
                tile[(wm * 64 + mt * 16 + quad * 4 + rr) * LDT + wn * 64 + nt * 16 + r16] =
                    acc[mt][nt][rr];
    __syncthreads();

    for (int i = tid; i < 128 * 32; i += 256) {
        int rr = i >> 5, cc = (i & 31) * 4;
        floatx4 v = *(const floatx4*)&tile[rr * LDT + cc];
        *(floatx4*)&C[(size_t)(bm + rr) * N_NODES + bn + cc] = v;
    }
}

// ---------------- launch ----------------
extern "C" void kernel_launch(void* const* d_in, const int* in_sizes, int n_in,
                              void* d_out, int out_size, void* d_ws, size_t ws_size,
                              hipStream_t stream) {
    const float* x        = (const float*)d_in[0];
    const int*   adj_rows = (const int*)d_in[1];
    const int*   adj_cols = (const int*)d_in[2];
    const float* adj_vals = (const float*)d_in[3];
    const float* W1       = (const float*)d_in[4];
    const float* W2       = (const float*)d_in[5];
    const float* W3       = (const float*)d_in[6];
    const int E = in_sizes[1];
    const int n = N_NODES;

    char* ws = (char*)d_ws;
    size_t off = 0;
    auto alloc = [&](size_t bytes) {
        void* p = ws + off;
        off = (off + bytes + 255) & ~(size_t)255;
        return p;
    };
    int*    deg     = (int*)alloc((size_t)n * 4);
    int*    csr_col = (int*)alloc((size_t)n * RCAP * 4);
    float*  csr_val = (float*)alloc((size_t)n * RCAP * 4);
    __bf16* w1th    = (__bf16*)alloc((size_t)H1DIM * F_INDIM * 2);
    __bf16* w1tl    = (__bf16*)alloc((size_t)H1DIM * F_INDIM * 2);
    __bf16* w23th   = (__bf16*)alloc((size_t)(2 * H2DIM) * H1DIM * 2);
    __bf16* w23tl   = (__bf16*)alloc((size_t)(2 * H2DIM) * H1DIM * 2);
    float*  support = (float*)alloc((size_t)n * H1DIM * 4);
    float*  t23     = (float*)alloc((size_t)n * 2 * H2DIM * 4);
    __bf16* zb      = (__bf16*)alloc((size_t)n * H2DIM * 2);

    float* out        = (float*)d_out;
    float* adj_recon  = out;
    float* z_out      = out + (size_t)n * n;
    float* mu_out     = z_out + (size_t)n * H2DIM;
    float* logvar_out = mu_out + (size_t)n * H2DIM;

    const int nc = (E + 255) / 256;

    hipMemsetAsync(deg, 0, (size_t)n * 4, stream);

    // scatter_edges (bucket CSR) || transpose_cast_w  -- both independent
    fused_scatter_transw<<<nc + 160, 256, 0, stream>>>(adj_rows, adj_cols, adj_vals,
                                                       deg, csr_col, csr_val, E, nc,
                                                       W1, W2, W3,
                                                       w1th, w1tl, w23th, w23tl);

    // gc1 dense part (needs transW)
    gemm1_mfma<<<(n / 64) * 2, 256, 0, stream>>>(x, w1th, w1tl, support);

    // gc2/gc3: spmm_h1 + gemm23 fused (h1 never hits global memory)
    spmm_gemm23<<<n / 16, 512, 0, stream>>>(deg, csr_col, csr_val, support,
                                            w23th, w23tl, t23);

    spmm_mu_logvar<<<n / 4, 256, 0, stream>>>(deg, csr_col, csr_val, t23,
                                              mu_out, z_out, logvar_out, zb);

    // decoder
    zzt_mfma<<<dim3(n / 128, n / 128), 256, 0, stream>>>(zb, adj_recon);
}

// Round 7
// 373.910 us; speedup vs baseline: 1.0433x; 1.0433x over previous
//
#include <hip/hip_runtime.h>
#include <hip/hip_bf16.h>

#define N_NODES 8192
#define F_INDIM 512
#define H1DIM   256
#define H2DIM   64
#define RCAP    128   // bucket capacity per row (max degree ~60, 12-sigma margin)

typedef __bf16 bf16x8 __attribute__((ext_vector_type(8)));
typedef __bf16 bf16x4 __attribute__((ext_vector_type(4)));
typedef __bf16 bf16x2 __attribute__((ext_vector_type(2)));
typedef float  floatx4 __attribute__((ext_vector_type(4)));
typedef float  floatx2 __attribute__((ext_vector_type(2)));

// ---------------- fused: scatter_bucket (blocks < nc) || transpose_cast_w ---
// Bucket CSR: slot = atomicAdd(deg[r]); edges land at r*RCAP + slot.
// No count/scan dispatches needed.
__global__ __launch_bounds__(256) void fused_scatter_transw(
        const int* __restrict__ rows, const int* __restrict__ cols,
        const float* __restrict__ vals, int* __restrict__ deg,
        int* __restrict__ csr_col, float* __restrict__ csr_val, int e, int nc,
        const float* __restrict__ W1, const float* __restrict__ W2,
        const float* __restrict__ W3,
        __bf16* __restrict__ w1th, __bf16* __restrict__ w1tl,
        __bf16* __restrict__ w23th, __bf16* __restrict__ w23tl) {
    __shared__ float tile[32][33];
    const int b = blockIdx.x;
    if (b < nc) {
        int i = b * 256 + threadIdx.x;
        if (i < e) {
            int r = rows[i];
            int slot = atomicAdd(&deg[r], 1);
            csr_col[(size_t)r * RCAP + slot] = cols[i];
            csr_val[(size_t)r * RCAP + slot] = vals[i];
        }
        return;
    }
    const int bb = b - nc;
    const float* src; __bf16 *oh, *ol; int N, rowoff, outld, kt, nt;
    if (bb < 128)      { src = W1; N = 256; oh = w1th;  ol = w1tl;  rowoff = 0;
                         outld = 512; kt = bb >> 3; nt = bb & 7; }
    else if (bb < 144) { src = W2; N = 64;  oh = w23th; ol = w23tl; rowoff = 0;
                         outld = 256; kt = (bb - 128) >> 1; nt = (bb - 128) & 1; }
    else               { src = W3; N = 64;  oh = w23th; ol = w23tl; rowoff = 64;
                         outld = 256; kt = (bb - 144) >> 1; nt = (bb - 144) & 1; }
    const int tx = threadIdx.x & 31, ty = threadIdx.x >> 5;   // 32 x 8
#pragma unroll
    for (int j = 0; j < 4; ++j)
        tile[ty + 8 * j][tx] = src[(size_t)(kt * 32 + ty + 8 * j) * N + nt * 32 + tx];
    __syncthreads();
#pragma unroll
    for (int j = 0; j < 4; ++j) {
        int n = nt * 32 + ty + 8 * j;
        int k = kt * 32 + tx;
        float v = tile[tx][ty + 8 * j];
        __bf16 h = (__bf16)v;
        oh[(size_t)(rowoff + n) * outld + k] = h;
        ol[(size_t)(rowoff + n) * outld + k] = (__bf16)(v - (float)h);
    }
}

// ---------------- gemm1: support = x @ W1 via split-bf16 MFMA ----------------
// BM=64, BN=128, BK=32, 4 waves (2x2), wave tile 32x64 (2x4 frags of 16x16x32)
// 3-term split: AhBh + AhBl + AlBh accumulated in f32 (~fp32 accuracy).
// A and B both staged through LDS: cooperative coalesced staging loads +
// broadcast LDS reads (B-direct-from-global regressed at 1 block/CU -- R6).
__global__ __launch_bounds__(256) void gemm1_mfma(const float* __restrict__ x,
                                                  const __bf16* __restrict__ bth,
                                                  const __bf16* __restrict__ btl,
                                                  float* __restrict__ C) {
    constexpr int K = F_INDIM, NN = H1DIM, LDSW = 40;
    __shared__ __bf16 Ah[64 * LDSW], Al[64 * LDSW], Bh[128 * LDSW], Bl[128 * LDSW];
    const int tid = threadIdx.x;
    const int g = blockIdx.x;
    const int m0 = (g >> 1) * 64, n0 = (g & 1) * 128;
    const int lane = tid & 63, wv = tid >> 6;
    const int wm = wv >> 1, wn = wv & 1;
    const int r16 = lane & 15, q = lane >> 4;
    const int sr = tid >> 2, sc = (tid & 3) * 8;   // A stage: 64 rows x 4 chunks of 8
    floatx4 acc[2][4] = {};

    for (int k0 = 0; k0 < K; k0 += 32) {
        floatx4 xa0 = *(const floatx4*)&x[(size_t)(m0 + sr) * K + k0 + sc];
        floatx4 xa1 = *(const floatx4*)&x[(size_t)(m0 + sr) * K + k0 + sc + 4];
        bf16x8 vbh[2], vbl[2];
#pragma unroll
        for (int v = 0; v < 2; ++v) {
            int id = v * 256 + tid;
            int br = id >> 2, bc = (id & 3) * 8;   // 128 rows x 4 chunks
            vbh[v] = *(const bf16x8*)&bth[(size_t)(n0 + br) * K + k0 + bc];
            vbl[v] = *(const bf16x8*)&btl[(size_t)(n0 + br) * K + k0 + bc];
        }
        bf16x8 va, va2;
#pragma unroll
        for (int j = 0; j < 4; ++j) {
            __bf16 h0 = (__bf16)xa0[j];
            va[j] = h0; va2[j] = (__bf16)(xa0[j] - (float)h0);
            __bf16 h1 = (__bf16)xa1[j];
            va[4 + j] = h1; va2[4 + j] = (__bf16)(xa1[j] - (float)h1);
        }
        __syncthreads();
        *(bf16x8*)&Ah[sr * LDSW + sc] = va;
        *(bf16x8*)&Al[sr * LDSW + sc] = va2;
#pragma unroll
        for (int v = 0; v < 2; ++v) {
            int id = v * 256 + tid;
            int br = id >> 2, bc = (id & 3) * 8;
            *(bf16x8*)&Bh[br * LDSW + bc] = vbh[v];
            *(bf16x8*)&Bl[br * LDSW + bc] = vbl[v];
        }
        __syncthreads();
        bf16x8 ah[2], al[2], bh[4], bl[4];
#pragma unroll
        for (int mt = 0; mt < 2; ++mt) {
            ah[mt] = *(const bf16x8*)&Ah[(wm * 32 + mt * 16 + r16) * LDSW + q * 8];
            al[mt] = *(const bf16x8*)&Al[(wm * 32 + mt * 16 + r16) * LDSW + q * 8];
        }
#pragma unroll
        for (int nt = 0; nt < 4; ++nt) {
            bh[nt] = *(const bf16x8*)&Bh[(wn * 64 + nt * 16 + r16) * LDSW + q * 8];
            bl[nt] = *(const bf16x8*)&Bl[(wn * 64 + nt * 16 + r16) * LDSW + q * 8];
        }
#pragma unroll
        for (int mt = 0; mt < 2; ++mt)
#pragma unroll
            for (int nt = 0; nt < 4; ++nt) {
                acc[mt][nt] = __builtin_amdgcn_mfma_f32_16x16x32_bf16(ah[mt], bh[nt], acc[mt][nt], 0, 0, 0);
                acc[mt][nt] = __builtin_amdgcn_mfma_f32_16x16x32_bf16(ah[mt], bl[nt], acc[mt][nt], 0, 0, 0);
                acc[mt][nt] = __builtin_amdgcn_mfma_f32_16x16x32_bf16(al[mt], bh[nt], acc[mt][nt], 0, 0, 0);
            }
    }
#pragma unroll
    for (int mt = 0; mt < 2; ++mt)
#pragma unroll
        for (int nt = 0; nt < 4; ++nt)
#pragma unroll
            for (int i = 0; i < 4; ++i) {
                int row = m0 + wm * 32 + mt * 16 + q * 4 + i;
                int col = n0 + wn * 64 + nt * 16 + r16;
                C[(size_t)row * NN + col] = acc[mt][nt][i];
            }
}

// ---------------- fused spmm_h1 + gemm23 (bucket CSR, unroll-8 gather) ------
// Phase 2 stages B through LDS (cooperative coalesced loads + broadcast reads).
__global__ __launch_bounds__(512) void spmm_gemm23(const int* __restrict__ rowdeg,
                                                   const int* __restrict__ csr_col,
                                                   const float* __restrict__ csr_val,
                                                   const float* __restrict__ support,
                                                   const __bf16* __restrict__ bth,
                                                   const __bf16* __restrict__ btl,
                                                   float* __restrict__ t23) {
    constexpr int LDA = 264;
    constexpr int LDSW = 40;
    __shared__ __bf16 Ah[16 * LDA], Al[16 * LDA];
    __shared__ __bf16 Bh[128 * LDSW], Bl[128 * LDSW];
    __shared__ int   s_col[8][64];
    __shared__ float s_val[8][64];
    const int tid = threadIdx.x;
    const int w = tid >> 6, lane = tid & 63;
    const int m0 = blockIdx.x * 16;

    const float2* in2 = (const float2*)support;
#pragma unroll
    for (int p = 0; p < 2; ++p) {
        const int coff = p * 64;
#pragma unroll
        for (int ri = 0; ri < 2; ++ri) {
            const int rl = w * 2 + ri;
            const int r = m0 + rl;
            const int beg = r * RCAP;
            const int deg = rowdeg[r];
            float ax = 0.f, ay = 0.f;
            for (int base = 0; base < deg; base += 64) {
                int m = deg - base; if (m > 64) m = 64;
                if (lane < m) {
                    s_col[w][lane] = csr_col[beg + base + lane];
                    s_val[w][lane] = csr_val[beg + base + lane];
                }
                int e = 0;
                for (; e + 8 <= m; e += 8) {
                    float2 xv[8]; float vv[8];
#pragma unroll
                    for (int j = 0; j < 8; ++j) {
                        xv[j] = in2[(size_t)s_col[w][e + j] * 128 + coff + lane];
                        vv[j] = s_val[w][e + j];
                    }
#pragma unroll
                    for (int j = 0; j < 8; ++j) { ax += vv[j] * xv[j].x; ay += vv[j] * xv[j].y; }
                }
                for (; e + 4 <= m; e += 4) {
                    float2 xv[4]; float vv[4];
#pragma unroll
                    for (int j = 0; j < 4; ++j) {
                        xv[j] = in2[(size_t)s_col[w][e + j] * 128 + coff + lane];
                        vv[j] = s_val[w][e + j];
                    }
#pragma unroll
                    for (int j = 0; j < 4; ++j) { ax += vv[j] * xv[j].x; ay += vv[j] * xv[j].y; }
                }
                for (; e < m; ++e) {
                    float2 xv = in2[(size_t)s_col[w][e] * 128 + coff + lane];
                    float v = s_val[w][e];
                    ax += v * xv.x;
                    ay += v * xv.y;
                }
            }
            float rx = fmaxf(ax, 0.f), ry = fmaxf(ay, 0.f);
            __bf16 hx = (__bf16)rx, hy = (__bf16)ry;
            bf16x2 hv = {hx, hy};
            bf16x2 lv = {(__bf16)(rx - (float)hx), (__bf16)(ry - (float)hy)};
            const int kb = p * 128 + lane * 2;
            *(bf16x2*)&Ah[rl * LDA + kb] = hv;
            *(bf16x2*)&Al[rl * LDA + kb] = lv;
        }
    }
    const int r16 = lane & 15, q = lane >> 4;
    const int br = tid >> 2, bc = (tid & 3) * 8;
    floatx4 acc = {};
    for (int k0 = 0; k0 < H1DIM; k0 += 32) {
        bf16x8 vbh = *(const bf16x8*)&bth[(size_t)br * H1DIM + k0 + bc];
        bf16x8 vbl = *(const bf16x8*)&btl[(size_t)br * H1DIM + k0 + bc];
        __syncthreads();
        *(bf16x8*)&Bh[br * LDSW + bc] = vbh;
        *(bf16x8*)&Bl[br * LDSW + bc] = vbl;
        __syncthreads();
        bf16x8 ah = *(const bf16x8*)&Ah[r16 * LDA + k0 + q * 8];
        bf16x8 al = *(const bf16x8*)&Al[r16 * LDA + k0 + q * 8];
        bf16x8 bh = *(const bf16x8*)&Bh[(w * 16 + r16) * LDSW + q * 8];
        bf16x8 bl = *(const bf16x8*)&Bl[(w * 16 + r16) * LDSW + q * 8];
        acc = __builtin_amdgcn_mfma_f32_16x16x32_bf16(ah, bh, acc, 0, 0, 0);
        acc = __builtin_amdgcn_mfma_f32_16x16x32_bf16(ah, bl, acc, 0, 0, 0);
        acc = __builtin_amdgcn_mfma_f32_16x16x32_bf16(al, bh, acc, 0, 0, 0);
    }
#pragma unroll
    for (int i = 0; i < 4; ++i) {
        int row = m0 + q * 4 + i;
        int col = w * 16 + r16;
        t23[(size_t)row * 128 + col] = acc[i];
    }
}

// ---------------- spmm23: mu/z/logvar/zb (bucket CSR, unroll-8) -------------
__global__ __launch_bounds__(256) void spmm_mu_logvar(const int* __restrict__ rowdeg,
                                                      const int* __restrict__ csr_col,
                                                      const float* __restrict__ csr_val,
                                                      const float* __restrict__ t23,
                                                      float* __restrict__ mu,
                                                      float* __restrict__ z,
                                                      float* __restrict__ logvar,
                                                      __bf16* __restrict__ zb) {
    __shared__ int   s_col[4][64];
    __shared__ float s_val[4][64];
    const int tid = threadIdx.x;
    const int w = tid >> 6, lane = tid & 63;
    const int r = blockIdx.x * 4 + w;
    const int beg = r * RCAP;
    const int deg = rowdeg[r];
    const float2* in2 = (const float2*)t23;
    float ax = 0.f, ay = 0.f;
    for (int base = 0; base < deg; base += 64) {
        int m = deg - base; if (m > 64) m = 64;
        if (lane < m) {
            s_col[w][lane] = csr_col[beg + base + lane];
            s_val[w][lane] = csr_val[beg + base + lane];
        }
        int e = 0;
        for (; e + 8 <= m; e += 8) {
            float2 xv[8]; float vv[8];
#pragma unroll
            for (int j = 0; j < 8; ++j) {
                xv[j] = in2[(size_t)s_col[w][e + j] * 64 + lane];
                vv[j] = s_val[w][e + j];
            }
#pragma unroll
            for (int j = 0; j < 8; ++j) { ax += vv[j] * xv[j].x; ay += vv[j] * xv[j].y; }
        }
        for (; e + 4 <= m; e += 4) {
            float2 xv[4]; float vv[4];
#pragma unroll
            for (int j = 0; j < 4; ++j) {
                xv[j] = in2[(size_t)s_col[w][e + j] * 64 + lane];
                vv[j] = s_val[w][e + j];
            }
#pragma unroll
            for (int j = 0; j < 4; ++j) { ax += vv[j] * xv[j].x; ay += vv[j] * xv[j].y; }
        }
        for (; e < m; ++e) {
            float2 xv = in2[(size_t)s_col[w][e] * 64 + lane];
            float v = s_val[w][e];
            ax += v * xv.x;
            ay += v * xv.y;
        }
    }
    if (lane < 32) {
        size_t o2 = (size_t)r * 32 + lane;
        float2 v = {ax, ay};
        ((float2*)mu)[o2] = v;
        ((float2*)z)[o2] = v;
        bf16x2 b = {(__bf16)ax, (__bf16)ay};
        *(bf16x2*)&zb[(size_t)r * H2DIM + lane * 2] = b;
    } else {
        size_t o2 = (size_t)r * 32 + (lane - 32);
        float2 v = {ax, ay};
        ((float2*)logvar)[o2] = v;
    }
}

// ---------------- adj_recon = z @ z^T: MFMA + LDS-staged plain f4 stores ----
__global__ __launch_bounds__(256) void zzt_mfma(const __bf16* __restrict__ z,
                                                float* __restrict__ C) {
    constexpr int LDT = 132;
    __shared__ float tile[128 * LDT];
    const int tid = threadIdx.x;
    const int lane = tid & 63;
    const int wave = tid >> 6;
    const int wm = wave >> 1, wn = wave & 1;
    const int bm = blockIdx.y * 128, bn = blockIdx.x * 128;
    const int m0 = bm + wm * 64;
    const int n0 = bn + wn * 64;
    const int r16 = lane & 15;
    const int quad = lane >> 4;

    floatx4 acc[4][4] = {};
    const char* zc = (const char*)z;

#pragma unroll
    for (int h = 0; h < 2; ++h) {
        bf16x8 a[4], b[4];
#pragma unroll
        for (int mt = 0; mt < 4; ++mt)
            a[mt] = *(const bf16x8*)(zc + (m0 + mt * 16 + r16) * 128 + h * 64 + quad * 16);
#pragma unroll
        for (int nt = 0; nt < 4; ++nt)
            b[nt] = *(const bf16x8*)(zc + (n0 + nt * 16 + r16) * 128 + h * 64 + quad * 16);
#pragma unroll
        for (int mt = 0; mt < 4; ++mt)
#pragma unroll
            for (int nt = 0; nt < 4; ++nt)
                acc[mt][nt] = __builtin_amdgcn_mfma_f32_16x16x32_bf16(a[mt], b[nt], acc[mt][nt], 0, 0, 0);
    }

#pragma unroll
    for (int mt = 0; mt < 4; ++mt)
#pragma unroll
        for (int nt = 0; nt < 4; ++nt)
#pragma unroll
            for (int rr = 0; rr < 4; ++rr)
                tile[(wm * 64 + mt * 16 + quad * 4 + rr) * LDT + wn * 64 + nt * 16 + r16] =
                    acc[mt][nt][rr];
    __syncthreads();

    for (int i = tid; i < 128 * 32; i += 256) {
        int rr = i >> 5, cc = (i & 31) * 4;
        floatx4 v = *(const floatx4*)&tile[rr * LDT + cc];
        *(floatx4*)&C[(size_t)(bm + rr) * N_NODES + bn + cc] = v;
    }
}

// ---------------- launch ----------------
extern "C" void kernel_launch(void* const* d_in, const int* in_sizes, int n_in,
                              void* d_out, int out_size, void* d_ws, size_t ws_size,
                              hipStream_t stream) {
    const float* x        = (const float*)d_in[0];
    const int*   adj_rows = (const int*)d_in[1];
    const int*   adj_cols = (const int*)d_in[2];
    const float* adj_vals = (const float*)d_in[3];
    const float* W1       = (const float*)d_in[4];
    const float* W2       = (const float*)d_in[5];
    const float* W3       = (const float*)d_in[6];
    const int E = in_sizes[1];
    const int n = N_NODES;

    char* ws = (char*)d_ws;
    size_t off = 0;
    auto alloc = [&](size_t bytes) {
        void* p = ws + off;
        off = (off + bytes + 255) & ~(size_t)255;
        return p;
    };
    int*    deg     = (int*)alloc((size_t)n * 4);
    int*    csr_col = (int*)alloc((size_t)n * RCAP * 4);
    float*  csr_val = (float*)alloc((size_t)n * RCAP * 4);
    __bf16* w1th    = (__bf16*)alloc((size_t)H1DIM * F_INDIM * 2);
    __bf16* w1tl    = (__bf16*)alloc((size_t)H1DIM * F_INDIM * 2);
    __bf16* w23th   = (__bf16*)alloc((size_t)(2 * H2DIM) * H1DIM * 2);
    __bf16* w23tl   = (__bf16*)alloc((size_t)(2 * H2DIM) * H1DIM * 2);
    float*  support = (float*)alloc((size_t)n * H1DIM * 4);
    float*  t23     = (float*)alloc((size_t)n * 2 * H2DIM * 4);
    __bf16* zb      = (__bf16*)alloc((size_t)n * H2DIM * 2);

    float* out        = (float*)d_out;
    float* adj_recon  = out;
    float* z_out      = out + (size_t)n * n;
    float* mu_out     = z_out + (size_t)n * H2DIM;
    float* logvar_out = mu_out + (size_t)n * H2DIM;

    const int nc = (E + 255) / 256;

    hipMemsetAsync(deg, 0, (size_t)n * 4, stream);

    // scatter_edges (bucket CSR) || transpose_cast_w  -- both independent
    fused_scatter_transw<<<nc + 160, 256, 0, stream>>>(adj_rows, adj_cols, adj_vals,
                                                       deg, csr_col, csr_val, E, nc,
                                                       W1, W2, W3,
                                                       w1th, w1tl, w23th, w23tl);

    // gc1 dense part (needs transW)
    gemm1_mfma<<<(n / 64) * 2, 256, 0, stream>>>(x, w1th, w1tl, support);

    // gc2/gc3: spmm_h1 + gemm23 fused (h1 never hits global memory)
    spmm_gemm23<<<n / 16, 512, 0, stream>>>(deg, csr_col, csr_val, support,
                                            w23th, w23tl, t23);

    spmm_mu_logvar<<<n / 4, 256, 0, stream>>>(deg, csr_col, csr_val, t23,
                                              mu_out, z_out, logvar_out, zb);

    // decoder
    zzt_mfma<<<dim3(n / 128, n / 128), 256, 0, stream>>>(zb, adj_recon);
}